// Round 1
// baseline (152.822 us; speedup 1.0000x reference)
//
#include <hip/hip_runtime.h>

#define WINDOW   512
#define STEPSZ   256
#define NFRAMES  127
#define NSAMP    32768
#define NBATCH   512
#define NFREQ    256

typedef __attribute__((ext_vector_type(8))) short short8;   // 8 x bf16 (4 VGPRs)
typedef __attribute__((ext_vector_type(4))) float f32x4;    // MFMA acc frag
typedef __attribute__((ext_vector_type(4))) float f4;

static __device__ __forceinline__ short f2bf(float x) {
    union { float f; unsigned u; } v; v.f = x;
    unsigned r = (v.u + 0x7fffu + ((v.u >> 16) & 1u)) >> 16;
    return (short)r;
}

// ---------------- kernel 1: normalize basis -> bf16 B^T [512 n][512 k] ----
__global__ __launch_bounds__(256) void prep_kernel(const float* __restrict__ br,
                                                   const float* __restrict__ bi,
                                                   short* __restrict__ Bn) {
    const int lane = threadIdx.x & 63;
    const int wid  = threadIdx.x >> 6;
    const int k    = blockIdx.x * 4 + wid;          // 64 blocks * 4 waves = 256 freqs
    const float* pr = br + (size_t)k * WINDOW + lane * 8;
    const float* pi = bi + (size_t)k * WINDOW + lane * 8;
    f4 r0 = *(const f4*)pr;
    f4 r1 = *(const f4*)(pr + 4);
    f4 i0 = *(const f4*)pi;
    f4 i1 = *(const f4*)(pi + 4);
    float ss = 0.f;
#pragma unroll
    for (int j = 0; j < 4; ++j)
        ss += r0[j]*r0[j] + r1[j]*r1[j] + i0[j]*i0[j] + i1[j]*i1[j];
#pragma unroll
    for (int d = 1; d < 64; d <<= 1) ss += __shfl_xor(ss, d, 64);
    const float inv = 1.0f / (sqrtf(ss) + 1e-8f);
    short8 hr, hi;
#pragma unroll
    for (int j = 0; j < 4; ++j) {
        hr[j]     = f2bf(r0[j] * inv);
        hr[j + 4] = f2bf(r1[j] * inv);
        hi[j]     = f2bf(i0[j] * inv);
        hi[j + 4] = f2bf(i1[j] * inv);
    }
    *(short8*)(Bn + (size_t)k * WINDOW + lane * 8)           = hr;   // real rows 0..255
    *(short8*)(Bn + (size_t)(NFREQ + k) * WINDOW + lane * 8) = hi;   // imag rows 256..511
}

// ---------------- kernel 2: fused norms + bf16 MFMA GEMM ------------------
// grid = 512 batches * 2 frame-tiles; block = 256 threads (4 waves)
// tile: BM=64 frames x BN=512 cols (wave w owns cols [w*128,(w+1)*128))
__global__ __launch_bounds__(256) void mel_kernel(const float* __restrict__ audio,
                                                  const short* __restrict__ Bn,
                                                  float* __restrict__ out) {
    __shared__ short lds[64 * 512];   // 64 KiB, XOR-swizzled wn tile (bf16)

    const int tid  = threadIdx.x;
    const int lane = tid & 63;
    const int wid  = tid >> 6;
    const int b    = blockIdx.x >> 1;
    const int f0   = (blockIdx.x & 1) * 64;

    float* out_norms = out;
    float* out_real  = out + 65024;                 // 512*127
    float* out_imag  = out + 65024 + 16646144;      // + 512*127*256

    const float* abase = audio + (size_t)b * NSAMP;

    // ---- Phase 1: per-frame norm + normalize + stage bf16 into LDS ----
    // wave handles one full row per iteration -> coalesced 2KB row reads,
    // conflict-free swizzled LDS writes.
    for (int it = 0; it < 16; ++it) {
        const int row = it * 4 + wid;               // 0..63
        const int fr  = f0 + row;
        const int frc = fr < NFRAMES ? fr : NFRAMES - 1;   // clamp pad row
        const float* p = abase + frc * STEPSZ + lane * 8;
        f4 v0 = *(const f4*)p;
        f4 v1 = *(const f4*)(p + 4);
        float ss = 0.f;
#pragma unroll
        for (int j = 0; j < 4; ++j) ss += v0[j]*v0[j] + v1[j]*v1[j];
#pragma unroll
        for (int d = 1; d < 64; d <<= 1) ss += __shfl_xor(ss, d, 64);
        const float nrm = sqrtf(ss);
        const float inv = 1.0f / (nrm + 1e-8f);
        if (lane == 0 && fr < NFRAMES) out_norms[b * NFRAMES + fr] = nrm;
        short8 h;
#pragma unroll
        for (int j = 0; j < 4; ++j) {
            h[j]     = f2bf(v0[j] * inv);
            h[j + 4] = f2bf(v1[j] * inv);
        }
        const int byt = row * 1024 + ((lane * 16) ^ ((row & 7) << 4));
        *(short8*)((char*)lds + byt) = h;
    }
    __syncthreads();

    // ---- Phase 2: K-loop, no barriers (whole K resident in LDS) ----
    const int n0    = wid * 128;
    const int rlane = lane & 15;
    const int kgrp  = lane >> 4;

    f32x4 acc[4][8];
#pragma unroll
    for (int mt = 0; mt < 4; ++mt)
#pragma unroll
        for (int nt = 0; nt < 8; ++nt) acc[mt][nt] = (f32x4)0.f;

#pragma unroll 4
    for (int kk = 0; kk < 16; ++kk) {
        short8 a[4], bf[8];
        const int kbyte = kk * 64 + kgrp * 16;
#pragma unroll
        for (int mt = 0; mt < 4; ++mt) {
            const int row = mt * 16 + rlane;
            const int byt = row * 1024 + (kbyte ^ ((row & 7) << 4));
            a[mt] = *(const short8*)((const char*)lds + byt);
        }
#pragma unroll
        for (int nt = 0; nt < 8; ++nt) {
            const int n = n0 + nt * 16 + rlane;
            bf[nt] = *(const short8*)(Bn + (size_t)n * WINDOW + kk * 32 + kgrp * 8);
        }
#pragma unroll
        for (int nt = 0; nt < 8; ++nt)
#pragma unroll
            for (int mt = 0; mt < 4; ++mt)
                acc[mt][nt] = __builtin_amdgcn_mfma_f32_16x16x32_bf16(a[mt], bf[nt], acc[mt][nt], 0, 0, 0);
    }

    // ---- Epilogue: C/D frag (col=lane&15, row=(lane>>4)*4+reg) -> global ----
#pragma unroll
    for (int mt = 0; mt < 4; ++mt) {
        const int fr_base = f0 + mt * 16 + kgrp * 4;
#pragma unroll
        for (int nt = 0; nt < 8; ++nt) {
            const int n = n0 + nt * 16 + rlane;
            float* dst = (n < NFREQ) ? out_real : out_imag;
            const int kcol = n & (NFREQ - 1);
#pragma unroll
            for (int j = 0; j < 4; ++j) {
                const int fr = fr_base + j;
                if (fr < NFRAMES)
                    dst[((size_t)b * NFRAMES + fr) * NFREQ + kcol] = acc[mt][nt][j];
            }
        }
    }
}

extern "C" void kernel_launch(void* const* d_in, const int* in_sizes, int n_in,
                              void* d_out, int out_size, void* d_ws, size_t ws_size,
                              hipStream_t stream) {
    const float* audio = (const float*)d_in[0];
    const float* br    = (const float*)d_in[1];
    const float* bi    = (const float*)d_in[2];
    float* out = (float*)d_out;
    short* Bn  = (short*)d_ws;              // 512*512 bf16 = 512 KiB

    prep_kernel<<<64, 256, 0, stream>>>(br, bi, Bn);
    mel_kernel<<<NBATCH * 2, 256, 0, stream>>>(audio, Bn, out);
}

// Round 3
// 152.241 us; speedup vs baseline: 1.0038x; 1.0038x over previous
//
#include <hip/hip_runtime.h>

#define WINDOW   512
#define STEPSZ   256
#define NFRAMES  127
#define NSAMP    32768
#define NBATCH   512
#define NFREQ    256
#define BM       64
#define SAMP_TILE 16640          // 65 * 256 samples per tile
#define NPS      65

typedef __attribute__((ext_vector_type(8))) short short8;   // 8 x bf16
typedef __attribute__((ext_vector_type(4))) short bf16x4;   // 4 x bf16
typedef __attribute__((ext_vector_type(4))) float f32x4;
typedef __attribute__((ext_vector_type(4))) float f4;

static __device__ __forceinline__ short f2bf(float x) {
    union { float f; unsigned u; } v; v.f = x;
    unsigned r = (v.u + 0x7fffu + ((v.u >> 16) & 1u)) >> 16;
    return (short)r;
}

// ---- kernel 1: normalize basis -> bf16 fragment-major layout in d_ws ----
// Bfrag element order: frag[(nt*16 + kk)*64 + (kgrp*16 + rlane)][8]
//   holds B[n = nt*16 + rlane][k = kk*32 + kgrp*8 + j]; real nt 0..15, imag 16..31.
// A wave's (nt,kk) fragment load = 64 lanes x 16 B contiguous = 1 KB coalesced.
__global__ __launch_bounds__(256) void prep_kernel(const float* __restrict__ br,
                                                   const float* __restrict__ bi,
                                                   short* __restrict__ Bf) {
    const int lane = threadIdx.x & 63;
    const int wid  = threadIdx.x >> 6;
    const int k    = blockIdx.x * 4 + wid;          // freq 0..255
    const float* pr = br + (size_t)k * WINDOW + lane * 8;
    const float* pi = bi + (size_t)k * WINDOW + lane * 8;
    f4 r0 = *(const f4*)pr;
    f4 r1 = *(const f4*)(pr + 4);
    f4 i0 = *(const f4*)pi;
    f4 i1 = *(const f4*)(pi + 4);
    float ss = 0.f;
#pragma unroll
    for (int j = 0; j < 4; ++j)
        ss += r0[j]*r0[j] + r1[j]*r1[j] + i0[j]*i0[j] + i1[j]*i1[j];
#pragma unroll
    for (int d = 1; d < 64; d <<= 1) ss += __shfl_xor(ss, d, 64);
    const float inv = 1.0f / (sqrtf(ss) + 1e-8f);
    short8 hr, hi;
#pragma unroll
    for (int j = 0; j < 4; ++j) {
        hr[j]     = f2bf(r0[j] * inv);
        hr[j + 4] = f2bf(r1[j] * inv);
        hi[j]     = f2bf(i0[j] * inv);
        hi[j + 4] = f2bf(i1[j] * inv);
    }
    // lane covers k-range [lane*8, lane*8+8): kk = lane>>2, kgrp = lane&3
    const int kk = lane >> 2, kgrp = lane & 3;
    const int rl  = k & 15;
    const int ntR = k >> 4;
    const int ntI = 16 + (k >> 4);
    *(short8*)(Bf + ((size_t)(ntR * 16 + kk) * 64 + kgrp * 16 + rl) * 8) = hr;
    *(short8*)(Bf + ((size_t)(ntI * 16 + kk) * 64 + kgrp * 16 + rl) * 8) = hi;
}

// ---- kernel 2: fused norms + bf16 MFMA GEMM --------------------------------
// grid = 512 batches * 2 frame-tiles; block = 256 threads (4 waves).
// LDS holds RAW bf16 samples (frames overlap 50% -> 33 KB, not 64 KB);
// output rows are scaled by 1/norm in the epilogue (GEMM is linear in A-row).
__global__ __launch_bounds__(256, 3) void mel_kernel(const float* __restrict__ audio,
                                                     const short* __restrict__ Bf,
                                                     float* __restrict__ out) {
    __shared__ short smp[SAMP_TILE];   // 33280 B, XOR-swizzled bf16 samples
    __shared__ float ps[NPS];          // per-256-sample-block sum of squares (f32)
    __shared__ float invn[BM];

    const int tid  = threadIdx.x;
    const int lane = tid & 63;
    const int wid  = tid >> 6;
    const int b    = blockIdx.x >> 1;
    const int f0   = (blockIdx.x & 1) * BM;

    float* out_norms = out;
    float* out_real  = out + 65024;
    float* out_imag  = out + 65024 + 16646144;

    const float* abase = audio + (size_t)b * NSAMP + f0 * STEPSZ;
    const int smax = NSAMP - f0 * STEPSZ - 4;     // clamp so reads stay in batch row

    // ---- Phase 1: load samples, f32 block partial sums, bf16 -> LDS ----
    // iteration: wave w handles 256-sample block j = it*4 + w (lane: 4 samples)
    for (int it = 0; it < 17; ++it) {
        const int j = it * 4 + wid;
        if (j >= NPS) break;
        const int sl  = j * 256 + lane * 4;
        const int slc = sl < smax ? sl : smax;
        f4 v = *(const f4*)(abase + slc);
        float ss = v[0]*v[0] + v[1]*v[1] + v[2]*v[2] + v[3]*v[3];
#pragma unroll
        for (int d = 1; d < 64; d <<= 1) ss += __shfl_xor(ss, d, 64);
        if (lane == 0) ps[j] = ss;
        bf16x4 h;
#pragma unroll
        for (int q = 0; q < 4; ++q) h[q] = f2bf(v[q]);
        const int byt = sl * 2;
        const int swz = byt ^ (((byt >> 9) & 7) << 4);   // bit3 untouched: 8B-safe
        *(bf16x4*)((char*)smp + swz) = h;
    }
    __syncthreads();

    // ---- norms (exact f32): frame r covers sample blocks r and r+1 ----
    if (tid < BM) {
        const int fr = f0 + tid;
        const float nrm = sqrtf(ps[tid] + ps[tid + 1]);
        if (fr < NFRAMES) out_norms[b * NFRAMES + fr] = nrm;
        invn[tid] = 1.0f / (nrm + 1e-8f);
    }
    __syncthreads();

    // ---- Phase 2: K-loop, no barriers ----
    const int rlane = lane & 15;
    const int kgrp  = lane >> 4;
    const int ntg0  = wid * 8;                   // global n-tile base (8 per wave)

    f32x4 acc[4][8];
#pragma unroll
    for (int mt = 0; mt < 4; ++mt)
#pragma unroll
        for (int nt = 0; nt < 8; ++nt) acc[mt][nt] = (f32x4)0.f;

#pragma unroll 4
    for (int kk = 0; kk < 16; ++kk) {
        short8 a[4], bb[8];
#pragma unroll
        for (int nt = 0; nt < 8; ++nt)
            bb[nt] = *(const short8*)(Bf + ((size_t)((ntg0 + nt) * 16 + kk) * 64 + lane) * 8);
#pragma unroll
        for (int mt = 0; mt < 4; ++mt) {
            // A(r,k) = smp[r*256 + k], r = mt*16+rlane, k = kk*32+kgrp*8
            const int byt = (mt * 16 + rlane) * 512 + kk * 64 + kgrp * 16;
            const int swz = byt ^ (((byt >> 9) & 7) << 4);
            a[mt] = *(const short8*)((const char*)smp + swz);
        }
#pragma unroll
        for (int nt = 0; nt < 8; ++nt)
#pragma unroll
            for (int mt = 0; mt < 4; ++mt)
                acc[mt][nt] = __builtin_amdgcn_mfma_f32_16x16x32_bf16(a[mt], bb[nt], acc[mt][nt], 0, 0, 0);
    }

    // ---- Epilogue: scale by 1/norm, store ----
#pragma unroll
    for (int mt = 0; mt < 4; ++mt) {
        const int r_base = mt * 16 + kgrp * 4;
#pragma unroll
        for (int nt = 0; nt < 8; ++nt) {
            const int n = (ntg0 + nt) * 16 + rlane;
            float* dst = (n < NFREQ) ? out_real : out_imag;
            const int kcol = n & (NFREQ - 1);
#pragma unroll
            for (int j = 0; j < 4; ++j) {
                const int r  = r_base + j;
                const int fr = f0 + r;
                if (fr < NFRAMES)
                    dst[((size_t)b * NFRAMES + fr) * NFREQ + kcol] = acc[mt][nt][j] * invn[r];
            }
        }
    }
}

extern "C" void kernel_launch(void* const* d_in, const int* in_sizes, int n_in,
                              void* d_out, int out_size, void* d_ws, size_t ws_size,
                              hipStream_t stream) {
    const float* audio = (const float*)d_in[0];
    const float* br    = (const float*)d_in[1];
    const float* bi    = (const float*)d_in[2];
    float* out = (float*)d_out;
    short* Bf  = (short*)d_ws;               // 512x512 bf16 = 512 KiB

    prep_kernel<<<64, 256, 0, stream>>>(br, bi, Bf);
    mel_kernel<<<NBATCH * 2, 256, 0, stream>>>(audio, Bf, out);
}

// Round 4
// 71.783 us; speedup vs baseline: 2.1289x; 2.1209x over previous
//
#include <hip/hip_runtime.h>

#define WINDOW   512
#define STEPSZ   256
#define NFRAMES  127
#define NSAMP    32768
#define NBATCH   512
#define NFREQ    256
#define BM       64
#define SAMP_TILE 16640          // 65 * 256 samples per tile

typedef __attribute__((ext_vector_type(8))) short short8;   // 8 x bf16
typedef __attribute__((ext_vector_type(4))) short bf16x4;   // 4 x bf16
typedef __attribute__((ext_vector_type(4))) float f32x4;
typedef __attribute__((ext_vector_type(4))) float f4;

static __device__ __forceinline__ short f2bf(float x) {
    union { float f; unsigned u; } v; v.f = x;
    unsigned r = (v.u + 0x7fffu + ((v.u >> 16) & 1u)) >> 16;
    return (short)r;
}
static __device__ __forceinline__ float bf2f(short h) {
    union { unsigned u; float f; } v; v.u = ((unsigned)(unsigned short)h) << 16;
    return v.f;
}

// ---- kernel 1: normalize basis -> bf16 fragment-major layout in d_ws ----
// frag[(ntg*16 + kk)*64 + (kgrp*16 + rlane)][8] holds
// B[n = ntg*16 + rlane][k = kk*32 + kgrp*8 + j]; real ntg 0..15, imag 16..31.
__global__ __launch_bounds__(256) void prep_kernel(const float* __restrict__ br,
                                                   const float* __restrict__ bi,
                                                   short* __restrict__ Bf) {
    const int lane = threadIdx.x & 63;
    const int wid  = threadIdx.x >> 6;
    const int k    = blockIdx.x * 4 + wid;          // freq 0..255
    const float* pr = br + (size_t)k * WINDOW + lane * 8;
    const float* pi = bi + (size_t)k * WINDOW + lane * 8;
    f4 r0 = *(const f4*)pr;
    f4 r1 = *(const f4*)(pr + 4);
    f4 i0 = *(const f4*)pi;
    f4 i1 = *(const f4*)(pi + 4);
    float ss = 0.f;
#pragma unroll
    for (int j = 0; j < 4; ++j)
        ss += r0[j]*r0[j] + r1[j]*r1[j] + i0[j]*i0[j] + i1[j]*i1[j];
#pragma unroll
    for (int d = 1; d < 64; d <<= 1) ss += __shfl_xor(ss, d, 64);
    const float inv = 1.0f / (sqrtf(ss) + 1e-8f);
    short8 hr, hi;
#pragma unroll
    for (int j = 0; j < 4; ++j) {
        hr[j]     = f2bf(r0[j] * inv);
        hr[j + 4] = f2bf(r1[j] * inv);
        hi[j]     = f2bf(i0[j] * inv);
        hi[j + 4] = f2bf(i1[j] * inv);
    }
    const int kk = lane >> 2, kgrp = lane & 3;
    const int rl  = k & 15;
    const int ntR = k >> 4;
    const int ntI = 16 + (k >> 4);
    *(short8*)(Bf + ((size_t)(ntR * 16 + kk) * 64 + kgrp * 16 + rl) * 8) = hr;
    *(short8*)(Bf + ((size_t)(ntI * 16 + kk) * 64 + kgrp * 16 + rl) * 8) = hi;
}

// ---- kernel 2: fused norms + bf16 MFMA GEMM --------------------------------
// grid = 512 b * 2 m-tiles * 4 n-chunks = 4096 blocks; 256 thr (4 waves).
// Per block: 64 frames x 128 cols. Per wave: 2 n-tiles (acc[4][2] keeps regs
// low -> 4 blocks/CU = 16 waves/CU). Norms computed FROM LDS bf16 (no serial
// shfl chain in the load phase).
__global__ __launch_bounds__(256, 4) void mel_kernel(const float* __restrict__ audio,
                                                     const short* __restrict__ Bf,
                                                     float* __restrict__ out) {
    __shared__ short smp[SAMP_TILE];   // 33280 B, XOR-swizzled bf16 samples
    __shared__ float invn[BM];

    const int tid  = threadIdx.x;
    const int lane = tid & 63;
    const int wid  = tid >> 6;

    // T1 bijective XCD swizzle (4096 % 8 == 0): consecutive logical blocks
    // (the 4 n-chunks + 2 m-tiles of one batch) land on one XCD -> audio L2 reuse.
    const int lb  = (blockIdx.x & 7) * 512 + (blockIdx.x >> 3);
    const int b   = lb >> 3;
    const int mt0 = (lb >> 2) & 1;
    const int nc  = lb & 3;
    const int f0  = mt0 * BM;

    float* out_norms = out;
    float* out_real  = out + 65024;
    float* out_imag  = out + 65024 + 16646144;

    const float* abase = audio + (size_t)b * NSAMP + f0 * STEPSZ;
    const int smax = NSAMP - f0 * STEPSZ - 4;

    // ---- Phase 1: pure streaming: HBM f32 -> bf16 -> swizzled LDS ----
#pragma unroll 4
    for (int it = 0; it < 17; ++it) {
        const int sl = it * 1024 + tid * 4;
        if (sl < SAMP_TILE) {
            const int slc = sl < smax ? sl : smax;
            f4 v = *(const f4*)(abase + slc);
            bf16x4 h;
#pragma unroll
            for (int q = 0; q < 4; ++q) h[q] = f2bf(v[q]);
            const int byt = sl * 2;
            const int swz = byt ^ (((byt >> 9) & 7) << 4);
            *(bf16x4*)((char*)smp + swz) = h;
        }
    }
    __syncthreads();

    // ---- norms from LDS bf16 (f32 accumulate): thread t -> frame t>>2 ----
    {
        const int f = tid >> 2, q = tid & 3;
        float ss = 0.f;
#pragma unroll
        for (int j = 0; j < 16; ++j) {
            const int byt = (f * 256 + q * 128 + j * 8) * 2;
            const int swz = byt ^ (((byt >> 9) & 7) << 4);
            short8 hv = *(const short8*)((const char*)smp + swz);
#pragma unroll
            for (int e = 0; e < 8; ++e) { const float x = bf2f(hv[e]); ss += x * x; }
        }
        ss += __shfl_xor(ss, 1, 64);
        ss += __shfl_xor(ss, 2, 64);
        const float nrm = sqrtf(ss);
        if (q == 0) {
            const int fr = f0 + f;
            if (fr < NFRAMES && nc == 0) out_norms[b * NFRAMES + fr] = nrm;
            invn[f] = 1.0f / (nrm + 1e-8f);
        }
    }
    __syncthreads();

    // ---- Phase 2: K-loop with manual B double-buffer ----
    const int rlane = lane & 15;
    const int kgrp  = lane >> 4;
    const int ntg0  = nc * 8 + wid * 2;          // global n-tile (2 per wave)

    f32x4 acc[4][2];
#pragma unroll
    for (int mt = 0; mt < 4; ++mt) { acc[mt][0] = (f32x4)0.f; acc[mt][1] = (f32x4)0.f; }

    const short* bp0 = Bf + ((size_t)(ntg0 + 0) * 16 * 64 + lane) * 8;
    const short* bp1 = Bf + ((size_t)(ntg0 + 1) * 16 * 64 + lane) * 8;
    short8 b0 = *(const short8*)bp0;
    short8 b1 = *(const short8*)bp1;

#pragma unroll 4
    for (int kk = 0; kk < 16; ++kk) {
        short8 a0, a1, a2, a3;
        {
            const int kb = kk * 64 + kgrp * 16;
            int byt;
            byt = (0 * 16 + rlane) * 512 + kb; a0 = *(const short8*)((const char*)smp + (byt ^ (((byt >> 9) & 7) << 4)));
            byt = (1 * 16 + rlane) * 512 + kb; a1 = *(const short8*)((const char*)smp + (byt ^ (((byt >> 9) & 7) << 4)));
            byt = (2 * 16 + rlane) * 512 + kb; a2 = *(const short8*)((const char*)smp + (byt ^ (((byt >> 9) & 7) << 4)));
            byt = (3 * 16 + rlane) * 512 + kb; a3 = *(const short8*)((const char*)smp + (byt ^ (((byt >> 9) & 7) << 4)));
        }
        short8 nb0 = b0, nb1 = b1;
        if (kk < 15) {
            nb0 = *(const short8*)(bp0 + (size_t)(kk + 1) * 512);
            nb1 = *(const short8*)(bp1 + (size_t)(kk + 1) * 512);
        }
        acc[0][0] = __builtin_amdgcn_mfma_f32_16x16x32_bf16(a0, b0, acc[0][0], 0, 0, 0);
        acc[1][0] = __builtin_amdgcn_mfma_f32_16x16x32_bf16(a1, b0, acc[1][0], 0, 0, 0);
        acc[2][0] = __builtin_amdgcn_mfma_f32_16x16x32_bf16(a2, b0, acc[2][0], 0, 0, 0);
        acc[3][0] = __builtin_amdgcn_mfma_f32_16x16x32_bf16(a3, b0, acc[3][0], 0, 0, 0);
        acc[0][1] = __builtin_amdgcn_mfma_f32_16x16x32_bf16(a0, b1, acc[0][1], 0, 0, 0);
        acc[1][1] = __builtin_amdgcn_mfma_f32_16x16x32_bf16(a1, b1, acc[1][1], 0, 0, 0);
        acc[2][1] = __builtin_amdgcn_mfma_f32_16x16x32_bf16(a2, b1, acc[2][1], 0, 0, 0);
        acc[3][1] = __builtin_amdgcn_mfma_f32_16x16x32_bf16(a3, b1, acc[3][1], 0, 0, 0);
        b0 = nb0; b1 = nb1;
    }

    // ---- Epilogue: scale by 1/norm, store ----
#pragma unroll
    for (int mt = 0; mt < 4; ++mt) {
        const int rbase = mt * 16 + kgrp * 4;
#pragma unroll
        for (int nt = 0; nt < 2; ++nt) {
            const int n = (ntg0 + nt) * 16 + rlane;
            float* dst = (n < NFREQ) ? out_real : out_imag;
            const int kcol = n & (NFREQ - 1);
#pragma unroll
            for (int j = 0; j < 4; ++j) {
                const int r  = rbase + j;
                const int fr = f0 + r;
                if (fr < NFRAMES)
                    dst[((size_t)b * NFRAMES + fr) * NFREQ + kcol] = acc[mt][nt][j] * invn[r];
            }
        }
    }
}

extern "C" void kernel_launch(void* const* d_in, const int* in_sizes, int n_in,
                              void* d_out, int out_size, void* d_ws, size_t ws_size,
                              hipStream_t stream) {
    const float* audio = (const float*)d_in[0];
    const float* br    = (const float*)d_in[1];
    const float* bi    = (const float*)d_in[2];
    float* out = (float*)d_out;
    short* Bf  = (short*)d_ws;               // 512x512 bf16 = 512 KiB

    prep_kernel<<<64, 256, 0, stream>>>(br, bi, Bf);
    mel_kernel<<<NBATCH * 2 * 4, 256, 0, stream>>>(audio, Bf, out);
}

// Round 5
// 68.477 us; speedup vs baseline: 2.2317x; 1.0483x over previous
//
#include <hip/hip_runtime.h>

#define WINDOW   512
#define STEPSZ   256
#define NFRAMES  127
#define NSAMP    32768
#define NBATCH   512
#define NFREQ    256
#define BM       64
#define SAMP_TILE 16640          // 65 * 256 samples per tile

typedef __attribute__((ext_vector_type(8))) short short8;   // 8 x bf16
typedef __attribute__((ext_vector_type(4))) short bf16x4;   // 4 x bf16
typedef __attribute__((ext_vector_type(4))) float f32x4;
typedef __attribute__((ext_vector_type(4))) float f4;

static __device__ __forceinline__ short f2bf(float x) {
    union { float f; unsigned u; } v; v.f = x;
    unsigned r = (v.u + 0x7fffu + ((v.u >> 16) & 1u)) >> 16;
    return (short)r;
}
static __device__ __forceinline__ float bf2f(short h) {
    union { unsigned u; float f; } v; v.u = ((unsigned)(unsigned short)h) << 16;
    return v.f;
}

// ---- kernel 1: normalize basis -> bf16 fragment-major layout in d_ws ----
// frag[(ntg*16 + kk)*64 + (kgrp*16 + rlane)][8] holds
// B[n = ntg*16 + rlane][k = kk*32 + kgrp*8 + j]; real ntg 0..15, imag 16..31.
__global__ __launch_bounds__(256) void prep_kernel(const float* __restrict__ br,
                                                   const float* __restrict__ bi,
                                                   short* __restrict__ Bf) {
    const int lane = threadIdx.x & 63;
    const int wid  = threadIdx.x >> 6;
    const int k    = blockIdx.x * 4 + wid;          // freq 0..255
    const float* pr = br + (size_t)k * WINDOW + lane * 8;
    const float* pi = bi + (size_t)k * WINDOW + lane * 8;
    f4 r0 = *(const f4*)pr;
    f4 r1 = *(const f4*)(pr + 4);
    f4 i0 = *(const f4*)pi;
    f4 i1 = *(const f4*)(pi + 4);
    float ss = 0.f;
#pragma unroll
    for (int j = 0; j < 4; ++j)
        ss += r0[j]*r0[j] + r1[j]*r1[j] + i0[j]*i0[j] + i1[j]*i1[j];
#pragma unroll
    for (int d = 1; d < 64; d <<= 1) ss += __shfl_xor(ss, d, 64);
    const float inv = 1.0f / (sqrtf(ss) + 1e-8f);
    short8 hr, hi;
#pragma unroll
    for (int j = 0; j < 4; ++j) {
        hr[j]     = f2bf(r0[j] * inv);
        hr[j + 4] = f2bf(r1[j] * inv);
        hi[j]     = f2bf(i0[j] * inv);
        hi[j + 4] = f2bf(i1[j] * inv);
    }
    const int kk = lane >> 2, kgrp = lane & 3;
    const int rl  = k & 15;
    const int ntR = k >> 4;
    const int ntI = 16 + (k >> 4);
    *(short8*)(Bf + ((size_t)(ntR * 16 + kk) * 64 + kgrp * 16 + rl) * 8) = hr;
    *(short8*)(Bf + ((size_t)(ntI * 16 + kk) * 64 + kgrp * 16 + rl) * 8) = hi;
}

// ---- kernel 2: fused norms + bf16 MFMA GEMM --------------------------------
// grid = 512 b * 2 m-tiles = 1024 blocks; 1024 thr (16 waves).
// One block = full 64x512 output tile: staging + norms done ONCE (no n-chunk
// redundancy). Wave w owns n-tiles {2w, 2w+1}. 52 VGPR -> 8 waves/SIMD;
// LDS 33.8 KB -> 2 blocks/CU = 32 waves/CU (100% occupancy).
__global__ __launch_bounds__(1024, 4) void mel_kernel(const float* __restrict__ audio,
                                                      const short* __restrict__ Bf,
                                                      float* __restrict__ out) {
    __shared__ short smp[SAMP_TILE];   // 33280 B, XOR-swizzled bf16 samples
    __shared__ float invn[BM];

    const int tid  = threadIdx.x;
    const int lane = tid & 63;
    const int wid  = tid >> 6;

    const int b   = blockIdx.x >> 1;
    const int mt0 = blockIdx.x & 1;
    const int f0  = mt0 * BM;

    float* out_norms = out;
    float* out_real  = out + 65024;
    float* out_imag  = out + 65024 + 16646144;

    const float* abase = audio + (size_t)b * NSAMP + f0 * STEPSZ;
    const int smax = NSAMP - f0 * STEPSZ - 4;

    // ---- Phase 1: pure streaming: HBM f32 -> bf16 -> swizzled LDS ----
#pragma unroll
    for (int it = 0; it < 5; ++it) {
        const int sl = it * 4096 + tid * 4;
        if (sl < SAMP_TILE) {
            const int slc = sl < smax ? sl : smax;
            f4 v = *(const f4*)(abase + slc);
            bf16x4 h;
#pragma unroll
            for (int q = 0; q < 4; ++q) h[q] = f2bf(v[q]);
            const int byt = sl * 2;
            const int swz = byt ^ (((byt >> 9) & 7) << 4);
            *(bf16x4*)((char*)smp + swz) = h;
        }
    }
    __syncthreads();

    // ---- norms from LDS bf16: 16 threads per frame, 32 samples each ----
    {
        const int f = tid >> 4, q = tid & 15;
        float ss = 0.f;
#pragma unroll
        for (int j = 0; j < 4; ++j) {
            const int byt = (f * 256 + q * 32 + j * 8) * 2;
            const int swz = byt ^ (((byt >> 9) & 7) << 4);
            short8 hv = *(const short8*)((const char*)smp + swz);
#pragma unroll
            for (int e = 0; e < 8; ++e) { const float x = bf2f(hv[e]); ss += x * x; }
        }
        ss += __shfl_xor(ss, 1, 64);
        ss += __shfl_xor(ss, 2, 64);
        ss += __shfl_xor(ss, 4, 64);
        ss += __shfl_xor(ss, 8, 64);
        const float nrm = sqrtf(ss);
        if (q == 0) {
            const int fr = f0 + f;
            if (fr < NFRAMES) out_norms[b * NFRAMES + fr] = nrm;
            invn[f] = 1.0f / (nrm + 1e-8f);
        }
    }
    __syncthreads();

    // ---- Phase 2: K-loop with manual B double-buffer ----
    const int rlane = lane & 15;
    const int kgrp  = lane >> 4;
    const int ntg0  = wid * 2;                   // n-tiles {2w, 2w+1}

    f32x4 acc[4][2];
#pragma unroll
    for (int mt = 0; mt < 4; ++mt) { acc[mt][0] = (f32x4)0.f; acc[mt][1] = (f32x4)0.f; }

    const short* bp0 = Bf + ((size_t)(ntg0 + 0) * 16 * 64 + lane) * 8;
    const short* bp1 = Bf + ((size_t)(ntg0 + 1) * 16 * 64 + lane) * 8;
    short8 b0 = *(const short8*)bp0;
    short8 b1 = *(const short8*)bp1;

#pragma unroll 4
    for (int kk = 0; kk < 16; ++kk) {
        short8 a0, a1, a2, a3;
        {
            const int kb = kk * 64 + kgrp * 16;
            int byt;
            byt = (0 * 16 + rlane) * 512 + kb; a0 = *(const short8*)((const char*)smp + (byt ^ (((byt >> 9) & 7) << 4)));
            byt = (1 * 16 + rlane) * 512 + kb; a1 = *(const short8*)((const char*)smp + (byt ^ (((byt >> 9) & 7) << 4)));
            byt = (2 * 16 + rlane) * 512 + kb; a2 = *(const short8*)((const char*)smp + (byt ^ (((byt >> 9) & 7) << 4)));
            byt = (3 * 16 + rlane) * 512 + kb; a3 = *(const short8*)((const char*)smp + (byt ^ (((byt >> 9) & 7) << 4)));
        }
        short8 nb0 = b0, nb1 = b1;
        if (kk < 15) {
            nb0 = *(const short8*)(bp0 + (size_t)(kk + 1) * 512);
            nb1 = *(const short8*)(bp1 + (size_t)(kk + 1) * 512);
        }
        acc[0][0] = __builtin_amdgcn_mfma_f32_16x16x32_bf16(a0, b0, acc[0][0], 0, 0, 0);
        acc[1][0] = __builtin_amdgcn_mfma_f32_16x16x32_bf16(a1, b0, acc[1][0], 0, 0, 0);
        acc[2][0] = __builtin_amdgcn_mfma_f32_16x16x32_bf16(a2, b0, acc[2][0], 0, 0, 0);
        acc[3][0] = __builtin_amdgcn_mfma_f32_16x16x32_bf16(a3, b0, acc[3][0], 0, 0, 0);
        acc[0][1] = __builtin_amdgcn_mfma_f32_16x16x32_bf16(a0, b1, acc[0][1], 0, 0, 0);
        acc[1][1] = __builtin_amdgcn_mfma_f32_16x16x32_bf16(a1, b1, acc[1][1], 0, 0, 0);
        acc[2][1] = __builtin_amdgcn_mfma_f32_16x16x32_bf16(a2, b1, acc[2][1], 0, 0, 0);
        acc[3][1] = __builtin_amdgcn_mfma_f32_16x16x32_bf16(a3, b1, acc[3][1], 0, 0, 0);
        b0 = nb0; b1 = nb1;
    }

    // ---- Epilogue: scale by 1/norm, store ----
#pragma unroll
    for (int mt = 0; mt < 4; ++mt) {
        const int rbase = mt * 16 + kgrp * 4;
#pragma unroll
        for (int nt = 0; nt < 2; ++nt) {
            const int n = (ntg0 + nt) * 16 + rlane;
            float* dst = (n < NFREQ) ? out_real : out_imag;
            const int kcol = n & (NFREQ - 1);
#pragma unroll
            for (int j = 0; j < 4; ++j) {
                const int r  = rbase + j;
                const int fr = f0 + r;
                if (fr < NFRAMES)
                    dst[((size_t)b * NFRAMES + fr) * NFREQ + kcol] = acc[mt][nt][j] * invn[r];
            }
        }
    }
}

extern "C" void kernel_launch(void* const* d_in, const int* in_sizes, int n_in,
                              void* d_out, int out_size, void* d_ws, size_t ws_size,
                              hipStream_t stream) {
    const float* audio = (const float*)d_in[0];
    const float* br    = (const float*)d_in[1];
    const float* bi    = (const float*)d_in[2];
    float* out = (float*)d_out;
    short* Bf  = (short*)d_ws;               // 512x512 bf16 = 512 KiB

    prep_kernel<<<64, 256, 0, stream>>>(br, bi, Bf);
    mel_kernel<<<NBATCH * 2, 1024, 0, stream>>>(audio, Bf, out);
}

// Round 6
// 67.683 us; speedup vs baseline: 2.2579x; 1.0117x over previous
//
#include <hip/hip_runtime.h>

#define WINDOW   512
#define STEPSZ   256
#define NFRAMES  127
#define NSAMP    32768
#define NBATCH   512
#define NFREQ    256
#define BM       64
#define SAMP_TILE 16640          // 65 * 256 samples per tile
#define NPS      65

typedef __attribute__((ext_vector_type(8))) short short8;   // 8 x bf16
typedef __attribute__((ext_vector_type(4))) float f32x4;
typedef __attribute__((ext_vector_type(4))) float f4;

static __device__ __forceinline__ short f2bf(float x) {
    union { float f; unsigned u; } v; v.f = x;
    unsigned r = (v.u + 0x7fffu + ((v.u >> 16) & 1u)) >> 16;
    return (short)r;
}

// ---- kernel 1: normalize basis -> bf16 fragment-major layout in d_ws ----
// frag[(ntg*16 + kk)*64 + (kgrp*16 + rlane)][8] holds
// B[n = ntg*16 + rlane][k = kk*32 + kgrp*8 + j]; real ntg 0..15, imag 16..31.
__global__ __launch_bounds__(256) void prep_kernel(const float* __restrict__ br,
                                                   const float* __restrict__ bi,
                                                   short* __restrict__ Bf) {
    const int lane = threadIdx.x & 63;
    const int wid  = threadIdx.x >> 6;
    const int k    = blockIdx.x * 4 + wid;          // freq 0..255
    const float* pr = br + (size_t)k * WINDOW + lane * 8;
    const float* pi = bi + (size_t)k * WINDOW + lane * 8;
    f4 r0 = *(const f4*)pr;
    f4 r1 = *(const f4*)(pr + 4);
    f4 i0 = *(const f4*)pi;
    f4 i1 = *(const f4*)(pi + 4);
    float ss = 0.f;
#pragma unroll
    for (int j = 0; j < 4; ++j)
        ss += r0[j]*r0[j] + r1[j]*r1[j] + i0[j]*i0[j] + i1[j]*i1[j];
#pragma unroll
    for (int d = 1; d < 64; d <<= 1) ss += __shfl_xor(ss, d, 64);
    const float inv = 1.0f / (sqrtf(ss) + 1e-8f);
    short8 hr, hi;
#pragma unroll
    for (int j = 0; j < 4; ++j) {
        hr[j]     = f2bf(r0[j] * inv);
        hr[j + 4] = f2bf(r1[j] * inv);
        hi[j]     = f2bf(i0[j] * inv);
        hi[j + 4] = f2bf(i1[j] * inv);
    }
    const int kk = lane >> 2, kgrp = lane & 3;
    const int rl  = k & 15;
    const int ntR = k >> 4;
    const int ntI = 16 + (k >> 4);
    *(short8*)(Bf + ((size_t)(ntR * 16 + kk) * 64 + kgrp * 16 + rl) * 8) = hr;
    *(short8*)(Bf + ((size_t)(ntI * 16 + kk) * 64 + kgrp * 16 + rl) * 8) = hi;
}

// ---- kernel 2: fused norms + bf16 MFMA GEMM --------------------------------
// grid = 512 b * 2 m-tiles = 1024 blocks; 1024 thr (16 waves).
// Phase 1 fuses the norm partial sums (per-256-sample chunk, one chunk per
// 32-lane half-wave, ss reduced in-register) into the streaming convert ->
// no separate norm phase, no LDS re-read. K-loop swizzle is algebraic:
// XOR value = ((rlane + (kk>=8))&7)<<4, precomputed as X0/X1.
__global__ __launch_bounds__(1024, 4) void mel_kernel(const float* __restrict__ audio,
                                                      const short* __restrict__ Bf,
                                                      float* __restrict__ out) {
    __shared__ short smp[SAMP_TILE];   // 33280 B, XOR-swizzled bf16 samples
    __shared__ float ps[NPS];
    __shared__ float invn[BM];

    const int tid  = threadIdx.x;
    const int lane = tid & 63;
    const int wid  = tid >> 6;

    const int b   = blockIdx.x >> 1;
    const int mt0 = blockIdx.x & 1;
    const int f0  = mt0 * BM;

    float* out_norms = out;
    float* out_real  = out + 65024;
    float* out_imag  = out + 65024 + 16646144;

    const float* abase = audio + (size_t)b * NSAMP + f0 * STEPSZ;
    const int smax = NSAMP - f0 * STEPSZ - 8;

    // ---- B-fragment prefetch (independent of LDS) ----
    const int rlane = lane & 15;
    const int kgrp  = lane >> 4;
    const int ntg0  = wid * 2;
    const short* bp0 = Bf + ((size_t)(ntg0 + 0) * 16 * 64 + lane) * 8;
    const short* bp1 = Bf + ((size_t)(ntg0 + 1) * 16 * 64 + lane) * 8;
    short8 b0 = *(const short8*)bp0;
    short8 b1 = *(const short8*)bp1;

    // ---- Phase 1: stream 8 samples/thread: f32 -> ss partial + bf16 LDS ----
#pragma unroll
    for (int it = 0; it < 3; ++it) {
        const int sl = it * 8192 + tid * 8;
        float ss = 0.f;
        if (sl < SAMP_TILE) {
            const int slc = sl < smax ? sl : smax;
            f4 v0 = *(const f4*)(abase + slc);
            f4 v1 = *(const f4*)(abase + slc + 4);
            short8 h;
#pragma unroll
            for (int q = 0; q < 4; ++q) {
                ss += v0[q]*v0[q] + v1[q]*v1[q];
                h[q]     = f2bf(v0[q]);
                h[q + 4] = f2bf(v1[q]);
            }
            const int byt = sl * 2;
            const int swz = byt ^ (((byt >> 9) & 7) << 4);
            *(short8*)((char*)smp + swz) = h;
        }
        // reduce ss across the 32 lanes sharing one 256-sample chunk
        ss += __shfl_xor(ss, 1, 64);
        ss += __shfl_xor(ss, 2, 64);
        ss += __shfl_xor(ss, 4, 64);
        ss += __shfl_xor(ss, 8, 64);
        ss += __shfl_xor(ss, 16, 64);
        const int chunk = (it * 8192 + tid * 8) >> 8;
        if ((tid & 31) == 0 && chunk < NPS) ps[chunk] = ss;
    }
    __syncthreads();

    // ---- norms: frame f covers chunks f, f+1 ----
    if (tid < BM) {
        const float nrm = sqrtf(ps[tid] + ps[tid + 1]);
        const int fr = f0 + tid;
        if (fr < NFRAMES) out_norms[b * NFRAMES + fr] = nrm;
        invn[tid] = 1.0f / (nrm + 1e-8f);
    }

    // ---- Phase 2: K-loop, algebraic swizzle, manual B double-buffer ----
    const int rb = rlane * 512 + kgrp * 16;          // unswizzled lane base
    const int X0 = (rlane & 7) << 4;
    const int X1 = ((rlane + 1) & 7) << 4;
    const char* sb = (const char*)smp;

    f32x4 acc[4][2];
#pragma unroll
    for (int mt = 0; mt < 4; ++mt) { acc[mt][0] = (f32x4)0.f; acc[mt][1] = (f32x4)0.f; }

#pragma unroll
    for (int kk = 0; kk < 16; ++kk) {
        const int X  = (kk < 8) ? X0 : X1;
        const int kb = kk * 64;
        short8 a0 = *(const short8*)(sb + (((rb + 0 * 8192) + kb) ^ X));
        short8 a1 = *(const short8*)(sb + (((rb + 1 * 8192) + kb) ^ X));
        short8 a2 = *(const short8*)(sb + (((rb + 2 * 8192) + kb) ^ X));
        short8 a3 = *(const short8*)(sb + (((rb + 3 * 8192) + kb) ^ X));
        short8 nb0 = b0, nb1 = b1;
        if (kk < 15) {
            nb0 = *(const short8*)(bp0 + (size_t)(kk + 1) * 512);
            nb1 = *(const short8*)(bp1 + (size_t)(kk + 1) * 512);
        }
        acc[0][0] = __builtin_amdgcn_mfma_f32_16x16x32_bf16(a0, b0, acc[0][0], 0, 0, 0);
        acc[1][0] = __builtin_amdgcn_mfma_f32_16x16x32_bf16(a1, b0, acc[1][0], 0, 0, 0);
        acc[2][0] = __builtin_amdgcn_mfma_f32_16x16x32_bf16(a2, b0, acc[2][0], 0, 0, 0);
        acc[3][0] = __builtin_amdgcn_mfma_f32_16x16x32_bf16(a3, b0, acc[3][0], 0, 0, 0);
        acc[0][1] = __builtin_amdgcn_mfma_f32_16x16x32_bf16(a0, b1, acc[0][1], 0, 0, 0);
        acc[1][1] = __builtin_amdgcn_mfma_f32_16x16x32_bf16(a1, b1, acc[1][1], 0, 0, 0);
        acc[2][1] = __builtin_amdgcn_mfma_f32_16x16x32_bf16(a2, b1, acc[2][1], 0, 0, 0);
        acc[3][1] = __builtin_amdgcn_mfma_f32_16x16x32_bf16(a3, b1, acc[3][1], 0, 0, 0);
        b0 = nb0; b1 = nb1;
    }
    __syncthreads();   // invn visible to all epilogue readers

    // ---- Epilogue: scale by 1/norm, store ----
#pragma unroll
    for (int mt = 0; mt < 4; ++mt) {
        const int rbase = mt * 16 + kgrp * 4;
#pragma unroll
        for (int nt = 0; nt < 2; ++nt) {
            const int n = (ntg0 + nt) * 16 + rlane;
            float* dst = (n < NFREQ) ? out_real : out_imag;
            const int kcol = n & (NFREQ - 1);
#pragma unroll
            for (int j = 0; j < 4; ++j) {
                const int r  = rbase + j;
                const int fr = f0 + r;
                if (fr < NFRAMES)
                    dst[((size_t)b * NFRAMES + fr) * NFREQ + kcol] = acc[mt][nt][j] * invn[r];
            }
        }
    }
}

extern "C" void kernel_launch(void* const* d_in, const int* in_sizes, int n_in,
                              void* d_out, int out_size, void* d_ws, size_t ws_size,
                              hipStream_t stream) {
    const float* audio = (const float*)d_in[0];
    const float* br    = (const float*)d_in[1];
    const float* bi    = (const float*)d_in[2];
    float* out = (float*)d_out;
    short* Bf  = (short*)d_ws;               // 512x512 bf16 = 512 KiB

    prep_kernel<<<64, 256, 0, stream>>>(br, bi, Bf);
    mel_kernel<<<NBATCH * 2, 1024, 0, stream>>>(audio, Bf, out);
}

// Round 7
// 66.917 us; speedup vs baseline: 2.2838x; 1.0115x over previous
//
#include <hip/hip_runtime.h>

#define WINDOW   512
#define STEPSZ   256
#define NFRAMES  127
#define NSAMP    32768
#define NBATCH   512
#define NFREQ    256
#define BM       64
#define SAMP_TILE 16640          // 65 * 256 samples per tile
#define NPS      65

typedef __attribute__((ext_vector_type(8))) short short8;   // 8 x bf16
typedef __attribute__((ext_vector_type(4))) float f32x4;
typedef __attribute__((ext_vector_type(4))) float f4;

// LDS swizzle: XOR rlane-bits (addr bits 9-11) into bits[6:8].
// K-loop read lanes (rlane,kgrp) then cover 32 bank-clusters x 2 lanes (free);
// phase-1 streaming writes see a constant XOR per aligned 512B window (free).
#define SWZ(byt) ((byt) ^ ((((byt) >> 9) & 7) << 6))

static __device__ __forceinline__ short f2bf(float x) {
    union { float f; unsigned u; } v; v.f = x;
    unsigned r = (v.u + 0x7fffu + ((v.u >> 16) & 1u)) >> 16;
    return (short)r;
}

// ---- kernel 1: normalize basis -> bf16 fragment-major layout in d_ws ----
// frag[(ntg*16 + kk)*64 + (kgrp*16 + rlane)][8] holds
// B[n = ntg*16 + rlane][k = kk*32 + kgrp*8 + j]; real ntg 0..15, imag 16..31.
__global__ __launch_bounds__(256) void prep_kernel(const float* __restrict__ br,
                                                   const float* __restrict__ bi,
                                                   short* __restrict__ Bf) {
    const int lane = threadIdx.x & 63;
    const int wid  = threadIdx.x >> 6;
    const int k    = blockIdx.x * 4 + wid;          // freq 0..255
    const float* pr = br + (size_t)k * WINDOW + lane * 8;
    const float* pi = bi + (size_t)k * WINDOW + lane * 8;
    f4 r0 = *(const f4*)pr;
    f4 r1 = *(const f4*)(pr + 4);
    f4 i0 = *(const f4*)pi;
    f4 i1 = *(const f4*)(pi + 4);
    float ss = 0.f;
#pragma unroll
    for (int j = 0; j < 4; ++j)
        ss += r0[j]*r0[j] + r1[j]*r1[j] + i0[j]*i0[j] + i1[j]*i1[j];
#pragma unroll
    for (int d = 1; d < 64; d <<= 1) ss += __shfl_xor(ss, d, 64);
    const float inv = 1.0f / (sqrtf(ss) + 1e-8f);
    short8 hr, hi;
#pragma unroll
    for (int j = 0; j < 4; ++j) {
        hr[j]     = f2bf(r0[j] * inv);
        hr[j + 4] = f2bf(r1[j] * inv);
        hi[j]     = f2bf(i0[j] * inv);
        hi[j + 4] = f2bf(i1[j] * inv);
    }
    const int kk = lane >> 2, kgrp = lane & 3;
    const int rl  = k & 15;
    const int ntR = k >> 4;
    const int ntI = 16 + (k >> 4);
    *(short8*)(Bf + ((size_t)(ntR * 16 + kk) * 64 + kgrp * 16 + rl) * 8) = hr;
    *(short8*)(Bf + ((size_t)(ntI * 16 + kk) * 64 + kgrp * 16 + rl) * 8) = hi;
}

// ---- kernel 2: fused norms + bf16 MFMA GEMM --------------------------------
// grid = 512 b * 2 m-tiles = 1024 blocks; 1024 thr (16 waves).
// Phase 1 fuses norm partials into the streaming convert. K-loop: conflict-free
// swizzled A reads + depth-3 rotating B prefetch (breaks per-iter L2 latency).
__global__ __launch_bounds__(1024, 4) void mel_kernel(const float* __restrict__ audio,
                                                      const short* __restrict__ Bf,
                                                      float* __restrict__ out) {
    __shared__ short smp[SAMP_TILE];   // 33280 B, swizzled bf16 samples
    __shared__ float ps[NPS];
    __shared__ float invn[BM];

    const int tid  = threadIdx.x;
    const int lane = tid & 63;
    const int wid  = tid >> 6;

    const int b   = blockIdx.x >> 1;
    const int mt0 = blockIdx.x & 1;
    const int f0  = mt0 * BM;

    float* out_norms = out;
    float* out_real  = out + 65024;
    float* out_imag  = out + 65024 + 16646144;

    const float* abase = audio + (size_t)b * NSAMP + f0 * STEPSZ;
    const int smax = NSAMP - f0 * STEPSZ - 8;

    const int rlane = lane & 15;
    const int kgrp  = lane >> 4;
    const int ntg0  = wid * 2;
    const short* bp0 = Bf + ((size_t)(ntg0 + 0) * 16 * 64 + lane) * 8;
    const short* bp1 = Bf + ((size_t)(ntg0 + 1) * 16 * 64 + lane) * 8;

    // ---- depth-3 B prefetch (independent of LDS phase) ----
    short8 bb[3][2];
#pragma unroll
    for (int d = 0; d < 3; ++d) {
        bb[d][0] = *(const short8*)(bp0 + (size_t)d * 512);
        bb[d][1] = *(const short8*)(bp1 + (size_t)d * 512);
    }

    // ---- Phase 1: stream 8 samples/thread: f32 -> ss partial + bf16 LDS ----
#pragma unroll
    for (int it = 0; it < 3; ++it) {
        const int sl = it * 8192 + tid * 8;
        float ss = 0.f;
        if (sl < SAMP_TILE) {
            const int slc = sl < smax ? sl : smax;
            f4 v0 = *(const f4*)(abase + slc);
            f4 v1 = *(const f4*)(abase + slc + 4);
            short8 h;
#pragma unroll
            for (int q = 0; q < 4; ++q) {
                ss += v0[q]*v0[q] + v1[q]*v1[q];
                h[q]     = f2bf(v0[q]);
                h[q + 4] = f2bf(v1[q]);
            }
            const int byt = sl * 2;
            *(short8*)((char*)smp + SWZ(byt)) = h;
        }
        ss += __shfl_xor(ss, 1, 64);
        ss += __shfl_xor(ss, 2, 64);
        ss += __shfl_xor(ss, 4, 64);
        ss += __shfl_xor(ss, 8, 64);
        ss += __shfl_xor(ss, 16, 64);
        const int chunk = (it * 8192 + tid * 8) >> 8;
        if ((tid & 31) == 0 && chunk < NPS) ps[chunk] = ss;
    }
    __syncthreads();

    // ---- norms: frame f covers chunks f, f+1 ----
    if (tid < BM) {
        const float nrm = sqrtf(ps[tid] + ps[tid + 1]);
        const int fr = f0 + tid;
        if (fr < NFRAMES) out_norms[b * NFRAMES + fr] = nrm;
        invn[tid] = 1.0f / (nrm + 1e-8f);
    }

    // ---- Phase 2: K-loop ----
    const int rb = rlane * 512 + kgrp * 16;          // unswizzled lane base
    const int X0 = (rlane & 7) << 6;
    const int X1 = ((rlane + 1) & 7) << 6;
    const char* sb = (const char*)smp;

    f32x4 acc[4][2];
#pragma unroll
    for (int mt = 0; mt < 4; ++mt) { acc[mt][0] = (f32x4)0.f; acc[mt][1] = (f32x4)0.f; }

#pragma unroll
    for (int kk = 0; kk < 16; ++kk) {
        const int X  = (kk < 8) ? X0 : X1;
        const int kb = kk * 64;
        short8 a0 = *(const short8*)(sb + ((rb + 0 * 8192 + kb) ^ X));
        short8 a1 = *(const short8*)(sb + ((rb + 1 * 8192 + kb) ^ X));
        short8 a2 = *(const short8*)(sb + ((rb + 2 * 8192 + kb) ^ X));
        short8 a3 = *(const short8*)(sb + ((rb + 3 * 8192 + kb) ^ X));
        const int cur = kk % 3;
        short8 cb0 = bb[cur][0];
        short8 cb1 = bb[cur][1];
        if (kk < 13) {
            bb[cur][0] = *(const short8*)(bp0 + (size_t)(kk + 3) * 512);
            bb[cur][1] = *(const short8*)(bp1 + (size_t)(kk + 3) * 512);
        }
        acc[0][0] = __builtin_amdgcn_mfma_f32_16x16x32_bf16(a0, cb0, acc[0][0], 0, 0, 0);
        acc[1][0] = __builtin_amdgcn_mfma_f32_16x16x32_bf16(a1, cb0, acc[1][0], 0, 0, 0);
        acc[2][0] = __builtin_amdgcn_mfma_f32_16x16x32_bf16(a2, cb0, acc[2][0], 0, 0, 0);
        acc[3][0] = __builtin_amdgcn_mfma_f32_16x16x32_bf16(a3, cb0, acc[3][0], 0, 0, 0);
        acc[0][1] = __builtin_amdgcn_mfma_f32_16x16x32_bf16(a0, cb1, acc[0][1], 0, 0, 0);
        acc[1][1] = __builtin_amdgcn_mfma_f32_16x16x32_bf16(a1, cb1, acc[1][1], 0, 0, 0);
        acc[2][1] = __builtin_amdgcn_mfma_f32_16x16x32_bf16(a2, cb1, acc[2][1], 0, 0, 0);
        acc[3][1] = __builtin_amdgcn_mfma_f32_16x16x32_bf16(a3, cb1, acc[3][1], 0, 0, 0);
    }
    __syncthreads();   // invn visible to all epilogue readers

    // ---- Epilogue: scale by 1/norm, store ----
#pragma unroll
    for (int mt = 0; mt < 4; ++mt) {
        const int rbase = mt * 16 + kgrp * 4;
#pragma unroll
        for (int nt = 0; nt < 2; ++nt) {
            const int n = (ntg0 + nt) * 16 + rlane;
            float* dst = (n < NFREQ) ? out_real : out_imag;
            const int kcol = n & (NFREQ - 1);
#pragma unroll
            for (int j = 0; j < 4; ++j) {
                const int r  = rbase + j;
                const int fr = f0 + r;
                if (fr < NFRAMES)
                    dst[((size_t)b * NFRAMES + fr) * NFREQ + kcol] = acc[mt][nt][j] * invn[r];
            }
        }
    }
}

extern "C" void kernel_launch(void* const* d_in, const int* in_sizes, int n_in,
                              void* d_out, int out_size, void* d_ws, size_t ws_size,
                              hipStream_t stream) {
    const float* audio = (const float*)d_in[0];
    const float* br    = (const float*)d_in[1];
    const float* bi    = (const float*)d_in[2];
    float* out = (float*)d_out;
    short* Bf  = (short*)d_ws;               // 512x512 bf16 = 512 KiB

    prep_kernel<<<64, 256, 0, stream>>>(br, bi, Bf);
    mel_kernel<<<NBATCH * 2, 1024, 0, stream>>>(audio, Bf, out);
}